// Round 2
// baseline (591.840 us; speedup 1.0000x reference)
//
#include <hip/hip_runtime.h>
#include <stdint.h>

#define BATCH 8
#define NPTS 8192
#define NGRP 512
#define KNN 32
#define NCH 6

#define FPS_T 256
#define FPS_PPT (NPTS / FPS_T)   // 32 points per thread

// --------- FPS kernel: one block per batch ---------
__global__ __launch_bounds__(FPS_T) void fps_kernel(const float* __restrict__ pts,
                                                    float* __restrict__ out_ctr) {
    __shared__ float xs[NPTS], ys[NPTS], zs[NPTS];
    __shared__ unsigned long long slots[2][FPS_T / 64];

    const int b   = blockIdx.x;
    const int tid = threadIdx.x;
    const float* base = pts + (size_t)b * NPTS * NCH;

    float x[FPS_PPT], y[FPS_PPT], z[FPS_PPT], dist[FPS_PPT];
#pragma unroll
    for (int j = 0; j < FPS_PPT; ++j) {
        int p = tid + j * FPS_T;
        x[j] = base[p * NCH + 0];
        y[j] = base[p * NCH + 1];
        z[j] = base[p * NCH + 2];
        xs[p] = x[j]; ys[p] = y[j]; zs[p] = z[j];
        dist[j] = 1e10f;
    }
    __syncthreads();

    int far = 0;
    float* ctr = out_ctr + (size_t)b * NGRP * 3;

    for (int g = 0; g < NGRP; ++g) {
        // centroid broadcast from LDS (all lanes same address -> free broadcast)
        float cx = xs[far], cy = ys[far], cz = zs[far];
        if (tid == 0) {
            ctr[g * 3 + 0] = cx;
            ctr[g * 3 + 1] = cy;
            ctr[g * 3 + 2] = cz;
        }

        // update running min-dist, track local argmax (first-index tie-break:
        // ascending j scan with strict >). Matches numpy elementwise semantics:
        // (dx^2 + dy^2) + dz^2, each op individually rounded (no FMA).
        float bestv = -1.0f;
        int bestj = 0;
#pragma unroll
        for (int j = 0; j < FPS_PPT; ++j) {
            float dx = __fsub_rn(x[j], cx);
            float dy = __fsub_rn(y[j], cy);
            float dz = __fsub_rn(z[j], cz);
            float d = __fadd_rn(__fadd_rn(__fmul_rn(dx, dx), __fmul_rn(dy, dy)),
                                __fmul_rn(dz, dz));
            float nd = fminf(dist[j], d);
            dist[j] = nd;
            if (nd > bestv) { bestv = nd; bestj = j; }
        }
        int bestp = tid + bestj * FPS_T;
        // max-key with min-index tie-break (dist >= 0 so raw bits are monotone)
        unsigned long long key =
            ((unsigned long long)__float_as_uint(bestv) << 13) |
            (unsigned)(8191 - bestp);

        // wave-level max reduce
#pragma unroll
        for (int s = 32; s > 0; s >>= 1) {
            unsigned long long o = __shfl_xor(key, s, 64);
            key = (o > key) ? o : key;
        }
        int wid = tid >> 6;
        if ((tid & 63) == 0) slots[g & 1][wid] = key;
        __syncthreads();

        unsigned long long best = slots[g & 1][0];
#pragma unroll
        for (int w = 1; w < FPS_T / 64; ++w) {
            unsigned long long o = slots[g & 1][w];
            best = (o > best) ? o : best;
        }
        far = 8191 - (int)(best & 8191ULL);
    }
}

// --------- kNN key: match reference einsum numerics ---------
// cc/xx: separate numpy ufuncs (x**2 then sum) -> sequential rounded ops.
// dot:   einsum inner loop `acc += a*b` FMA-contracted, c ascending:
//        dot = fma(cz,z, fma(cy,y, rn(cx*x)))
__device__ __forceinline__ unsigned long long knn_key(const float* __restrict__ base,
                                                      int p, float cx, float cy,
                                                      float cz, float cc) {
    float x = base[p * NCH + 0];
    float y = base[p * NCH + 1];
    float z = base[p * NCH + 2];
    float xx = __fadd_rn(__fadd_rn(__fmul_rn(x, x), __fmul_rn(y, y)), __fmul_rn(z, z));
    float dt = fmaf(cz, z, fmaf(cy, y, __fmul_rn(cx, x)));
    float d2 = __fsub_rn(__fadd_rn(cc, xx), __fmul_rn(2.0f, dt));
    unsigned int bits = __float_as_uint(d2);
    // map float to order-preserving uint (d2 can be slightly negative)
    unsigned int ord = bits ^ ((unsigned)((int)bits >> 31) | 0x80000000u);
    return ((unsigned long long)ord << 13) | (unsigned)p;
}

// --------- kNN + gather: one wave per (b,g) center ---------
__global__ __launch_bounds__(64) void knn_kernel(const float* __restrict__ pts,
                                                 const float* __restrict__ ctr,
                                                 float* __restrict__ out_nb) {
    const int bg   = blockIdx.x;       // b*NGRP + g
    const int b    = bg >> 9;
    const int lane = threadIdx.x & 63;
    const float* base = pts + (size_t)b * NPTS * NCH;

    const float cx = ctr[bg * 3 + 0];
    const float cy = ctr[bg * 3 + 1];
    const float cz = ctr[bg * 3 + 2];
    const float cc = __fadd_rn(__fadd_rn(__fmul_rn(cx, cx), __fmul_rn(cy, cy)),
                               __fmul_rn(cz, cz));

    // chunk 0 -> bitonic sort 64 keys across the wave (ascending by lane)
    unsigned long long R = knn_key(base, lane, cx, cy, cz, cc);
#pragma unroll
    for (int k = 2; k <= 64; k <<= 1) {
#pragma unroll
        for (int j = k >> 1; j > 0; j >>= 1) {
            unsigned long long o = __shfl_xor(R, j, 64);
            bool takeMin = (((lane & k) == 0) == ((lane & j) == 0));
            unsigned long long mn = (o < R) ? o : R;
            unsigned long long mx = (o < R) ? R : o;
            R = takeMin ? mn : mx;
        }
    }
    unsigned long long R31 = __shfl(R, 31, 64);

    // stream remaining chunks; insert only candidates beating current 32nd
    for (int c = 1; c < NPTS / 64; ++c) {
        unsigned long long key = knn_key(base, c * 64 + lane, cx, cy, cz, cc);
        unsigned long long qual = __ballot(key < R31);
        while (qual) {
            int src = __ffsll(qual) - 1;
            qual &= qual - 1;
            unsigned long long bk = __shfl(key, src, 64);
            int rank = __popcll(__ballot(R < bk));
            unsigned long long Rp = __shfl_up(R, 1, 64);
            R = (lane == rank) ? bk : ((lane > rank) ? Rp : R);
            R31 = __shfl(R, 31, 64);
        }
    }

    // gather: lanes 0..31 hold the sorted top-32 (ascending d2, index tie-break)
    if (lane < KNN) {
        int idx = (int)(R & 8191ULL);
        const float* s = base + (size_t)idx * NCH;
        float* d = out_nb + ((size_t)bg * KNN + lane) * NCH;
        d[0] = s[0] - cx;
        d[1] = s[1] - cy;
        d[2] = s[2] - cz;
        d[3] = s[3];
        d[4] = s[4];
        d[5] = s[5];
    }
}

extern "C" void kernel_launch(void* const* d_in, const int* in_sizes, int n_in,
                              void* d_out, int out_size, void* d_ws, size_t ws_size,
                              hipStream_t stream) {
    const float* pts = (const float*)d_in[0];
    float* out = (float*)d_out;
    float* out_nb  = out;                                    // (8,512,32,6)
    float* out_ctr = out + (size_t)BATCH * NGRP * KNN * NCH; // (8,512,3)

    hipLaunchKernelGGL(fps_kernel, dim3(BATCH), dim3(FPS_T), 0, stream, pts, out_ctr);
    hipLaunchKernelGGL(knn_kernel, dim3(BATCH * NGRP), dim3(64), 0, stream,
                       pts, out_ctr, out_nb);
}